// Round 1
// baseline (929.914 us; speedup 1.0000x reference)
//
#include <hip/hip_runtime.h>
#include <stdint.h>
#include <stddef.h>

// ---------------------------------------------------------------------------
// VQ-VAE quantizer, MI355X.
// dist(n,k) = ||x_n||^2 + ||w_k||^2 - 2 x_n.w_k ; argmin_k fused into GEMM.
// fp32 emulated via bf16 split: A=[x_hi,x_hi,x_lo], B=[w_hi,w_lo,w_hi],
// inner dim 384 -> hi*hi + hi*lo + lo*hi.  Rows with top2 gap < TAU get an
// exact fp32 recompute (refine kernel) so bf16 rounding can't flip argmin.
// ---------------------------------------------------------------------------

#define N_ROWS   16384      // B*H*W = 16*32*32
#define K_CODES  8192
#define C_DIM    128
#define KD       384        // packed inner dim (3 x 128)
#define TAU      1e-3f

typedef short s16x8 __attribute__((ext_vector_type(8)));
typedef float f32x4 __attribute__((ext_vector_type(4)));

static __device__ __forceinline__ unsigned short f2bf(float f) {
  unsigned u = __float_as_uint(f);
  u += 0x7fffu + ((u >> 16) & 1u);   // RNE
  return (unsigned short)(u >> 16);
}
static __device__ __forceinline__ float bf2f(unsigned short h) {
  return __uint_as_float(((unsigned)h) << 16);
}

// ---------------- prep: pack encodings -> A [N, 384] bf16, xnorm -----------
// x[n,c] = enc[b,c,h,w], n = b*1024 + h*32 + w.  One wave per row.
__global__ void prep_x(const float* __restrict__ enc,
                       unsigned short* __restrict__ A,
                       float* __restrict__ xnorm) {
  int wave = threadIdx.x >> 6, lane = threadIdx.x & 63;
  int n = blockIdx.x * 4 + wave;
  int b = n >> 10, hw = n & 1023;
  const float* base = enc + ((size_t)b * 128) * 1024 + hw;
  float x0 = base[(size_t)lane * 1024];
  float x1 = base[(size_t)(lane + 64) * 1024];
  float s = x0 * x0 + x1 * x1;
  #pragma unroll
  for (int m = 1; m <= 32; m <<= 1) s += __shfl_xor(s, m);
  if (lane == 0) xnorm[n] = s;
  unsigned short h0 = f2bf(x0), h1 = f2bf(x1);
  unsigned short l0 = f2bf(x0 - bf2f(h0)), l1 = f2bf(x1 - bf2f(h1));
  unsigned short* row = A + (size_t)n * KD;
  row[lane]       = h0; row[lane + 64]  = h1;   // [0:128]   hi
  row[128 + lane] = h0; row[192 + lane] = h1;   // [128:256] hi
  row[256 + lane] = l0; row[320 + lane] = l1;   // [256:384] lo
}

// ---------------- prep: pack weight -> Bp [K, 384] bf16, wnorm -------------
__global__ void prep_w(const float* __restrict__ w,
                       unsigned short* __restrict__ Bp,
                       float* __restrict__ wnorm) {
  int wave = threadIdx.x >> 6, lane = threadIdx.x & 63;
  int k = blockIdx.x * 4 + wave;
  const float* base = w + (size_t)k * C_DIM;
  float x0 = base[lane], x1 = base[lane + 64];
  float s = x0 * x0 + x1 * x1;
  #pragma unroll
  for (int m = 1; m <= 32; m <<= 1) s += __shfl_xor(s, m);
  if (lane == 0) wnorm[k] = s;
  unsigned short h0 = f2bf(x0), h1 = f2bf(x1);
  unsigned short l0 = f2bf(x0 - bf2f(h0)), l1 = f2bf(x1 - bf2f(h1));
  unsigned short* row = Bp + (size_t)k * KD;
  row[lane]       = h0; row[lane + 64]  = h1;   // hi
  row[128 + lane] = l0; row[192 + lane] = l1;   // lo
  row[256 + lane] = h0; row[320 + lane] = h1;   // hi
}

// ---------------- main GEMM + fused per-row top-2 argmin -------------------
// Grid: (64 colblocks, 128 rowblocks); block tile 128 rows x 128 codes,
// inner 384 swept in 4 chunks of 96.  512 thr = 8 waves (2 row x 4 col),
// wave computes 4x2 tiles of 16x16 via v_mfma_f32_16x16x32_bf16.
// LDS: A[128][104] + B[128][104] bf16 (stride 104 = 96+8 pad -> 2-way free).
__global__ __launch_bounds__(512, 2) void gemm_argmin(
    const unsigned short* __restrict__ Ag, const unsigned short* __restrict__ Bg,
    const float* __restrict__ xnorm, const float* __restrict__ wnorm,
    float* __restrict__ pd1, unsigned* __restrict__ pc1, float* __restrict__ pd2)
{
  __shared__ __align__(16) unsigned short sm[2 * 128 * 104];
  unsigned short* As = sm;
  unsigned short* Bs = sm + 128 * 104;
  const int tid = threadIdx.x;
  const int lane = tid & 63, wave = tid >> 6;
  const int wr = wave >> 2, wc = wave & 3;      // wave grid 2 x 4
  const int m = lane & 15, q = lane >> 4;
  const int row0 = blockIdx.y * 128, col0 = blockIdx.x * 128;

  f32x4 acc[4][2];
  #pragma unroll
  for (int i = 0; i < 4; ++i)
    #pragma unroll
    for (int j = 0; j < 2; ++j)
      acc[i][j] = (f32x4){0.f, 0.f, 0.f, 0.f};

  for (int kc = 0; kc < 4; ++kc) {
    if (kc) __syncthreads();
    #pragma unroll
    for (int it = 0; it < 3; ++it) {            // stage A chunk [128 x 96]
      int u = it * 512 + tid;
      int row = u / 12, cu = u % 12;
      *(uint4*)(As + row * 104 + cu * 8) =
        *(const uint4*)(Ag + (size_t)(row0 + row) * KD + kc * 96 + cu * 8);
    }
    #pragma unroll
    for (int it = 0; it < 3; ++it) {            // stage B chunk [128 x 96]
      int u = it * 512 + tid;
      int row = u / 12, cu = u % 12;
      *(uint4*)(Bs + row * 104 + cu * 8) =
        *(const uint4*)(Bg + (size_t)(col0 + row) * KD + kc * 96 + cu * 8);
    }
    __syncthreads();
    #pragma unroll
    for (int ks = 0; ks < 3; ++ks) {
      s16x8 a[4], b[2];
      #pragma unroll
      for (int ti = 0; ti < 4; ++ti) {
        int rl = 64 * wr + 16 * ti + m;         // A row = lane&15
        a[ti] = *(const s16x8*)(As + rl * 104 + ks * 32 + q * 8);
      }
      #pragma unroll
      for (int tj = 0; tj < 2; ++tj) {
        int cl = 32 * wc + 16 * tj + m;         // B row (code) = lane&15
        b[tj] = *(const s16x8*)(Bs + cl * 104 + ks * 32 + q * 8);
      }
      #pragma unroll
      for (int ti = 0; ti < 4; ++ti)
        #pragma unroll
        for (int tj = 0; tj < 2; ++tj)
          acc[ti][tj] = __builtin_amdgcn_mfma_f32_16x16x32_bf16(
              a[ti], b[tj], acc[ti][tj], 0, 0, 0);
    }
  }

  // ---- epilogue: dist + per-row top2; C/D layout col=lane&15, row=4q+r ----
  __syncthreads();
  float*    ed1 = (float*)sm;                    // [4][128]
  unsigned* ec1 = (unsigned*)sm + 512;
  float*    ed2 = (float*)sm + 1024;
  float wn[2];
  #pragma unroll
  for (int tj = 0; tj < 2; ++tj) wn[tj] = wnorm[col0 + 32 * wc + 16 * tj + m];

  #pragma unroll
  for (int ti = 0; ti < 4; ++ti) {
    #pragma unroll
    for (int r = 0; r < 4; ++r) {
      int row_l = 64 * wr + 16 * ti + 4 * q + r;
      float xn = xnorm[row0 + row_l];
      float dd0 = (xn + wn[0]) - 2.0f * acc[ti][0][r];
      float dd1 = (xn + wn[1]) - 2.0f * acc[ti][1][r];
      unsigned ca = (unsigned)(col0 + 32 * wc + m), cb = ca + 16;
      float d1, d2; unsigned c1;
      if (dd1 < dd0) { d1 = dd1; c1 = cb; d2 = dd0; }
      else           { d1 = dd0; c1 = ca; d2 = dd1; }   // tie -> lower col
      #pragma unroll
      for (int s = 1; s <= 8; s <<= 1) {
        float    od1 = __shfl_xor(d1, s);
        unsigned oc1 = (unsigned)__shfl_xor((int)c1, s);
        float    od2 = __shfl_xor(d2, s);
        float nd2 = fminf(fminf(d2, od2), fmaxf(d1, od1));
        if (od1 < d1 || (od1 == d1 && oc1 < c1)) { d1 = od1; c1 = oc1; }
        d2 = nd2;
      }
      if (m == 0) {
        ed1[wc * 128 + row_l] = d1;
        ec1[wc * 128 + row_l] = c1;
        ed2[wc * 128 + row_l] = d2;
      }
    }
  }
  __syncthreads();
  if (tid < 128) {                               // merge 4 col-groups (asc col)
    float d1 = ed1[tid]; unsigned c1 = ec1[tid]; float d2 = ed2[tid];
    #pragma unroll
    for (int w2 = 1; w2 < 4; ++w2) {
      float od1 = ed1[w2 * 128 + tid], od2 = ed2[w2 * 128 + tid];
      float nd2 = fminf(fminf(d2, od2), fmaxf(d1, od1));
      if (od1 < d1) { d1 = od1; c1 = ec1[w2 * 128 + tid]; }
      d2 = nd2;
    }
    size_t pi = (size_t)blockIdx.x * N_ROWS + (size_t)(row0 + tid);
    pd1[pi] = d1; pc1[pi] = c1; pd2[pi] = d2;
  }
}

// ---------------- merge partials across 64 colblocks -----------------------
__global__ void merge_partials(const float* __restrict__ pd1,
                               const unsigned* __restrict__ pc1,
                               const float* __restrict__ pd2,
                               int* __restrict__ ids, unsigned* __restrict__ flags,
                               float* __restrict__ out_ids) {
  int row = blockIdx.x * 256 + threadIdx.x;
  float d1 = pd1[row]; unsigned c1 = pc1[row]; float d2 = pd2[row];
  for (int cb = 1; cb < 64; ++cb) {              // ascending col -> first-min tie
    size_t i = (size_t)cb * N_ROWS + row;
    float od1 = pd1[i], od2 = pd2[i];
    float nd2 = fminf(fminf(d2, od2), fmaxf(d1, od1));
    if (od1 < d1) { d1 = od1; c1 = pc1[i]; }
    d2 = nd2;
  }
  ids[row] = (int)c1;
  flags[row] = (d2 - d1 < TAU) ? 1u : 0u;
  out_ids[row] = (float)c1;
}

// ---------------- exact fp32 recompute for near-tie rows -------------------
__global__ void refine_rows(const float* __restrict__ enc,
                            const float* __restrict__ w,
                            const float* __restrict__ wnorm,
                            const unsigned* __restrict__ flags,
                            int* __restrict__ ids, float* __restrict__ out_ids) {
  __shared__ float xrow[C_DIM];
  __shared__ unsigned long long red[256];
  int tid = threadIdx.x;
  for (int rr = 0; rr < 64; ++rr) {
    int row = blockIdx.x * 64 + rr;
    if (!flags[row]) continue;                   // block-uniform branch
    int b = row >> 10, hw = row & 1023;
    if (tid < C_DIM) xrow[tid] = enc[((size_t)(b * 128 + tid)) * 1024 + hw];
    __syncthreads();
    float xn = 0.f;
    for (int c = 0; c < C_DIM; ++c) xn += xrow[c] * xrow[c];
    unsigned long long best = ~0ull;
    for (int k = tid; k < K_CODES; k += 256) {
      const float* wk = w + (size_t)k * C_DIM;
      float S = 0.f;
      for (int c = 0; c < C_DIM; ++c) S = fmaf(xrow[c], wk[c], S);
      float d = (xn + wnorm[k]) - 2.0f * S;
      unsigned long long key =
          ((unsigned long long)__float_as_uint(d) << 32) | (unsigned)k;
      best = best < key ? best : key;            // d>0 -> bits monotone; tie->low k
    }
    red[tid] = best;
    __syncthreads();
    for (int s = 128; s > 0; s >>= 1) {
      if (tid < s) red[tid] = red[tid] < red[tid + s] ? red[tid] : red[tid + s];
      __syncthreads();
    }
    if (tid == 0) {
      int k = (int)(red[0] & 0xffffffffu);
      ids[row] = k;
      out_ids[row] = (float)k;
    }
    __syncthreads();
  }
}

// ---------------- scatter stats --------------------------------------------
__global__ void scatter_counts(const int* __restrict__ ids, float* counts) {
  int n = blockIdx.x * 256 + threadIdx.x;
  unsafeAtomicAdd(&counts[ids[n]], 1.0f);
}
__global__ void scatter_sums(const float* __restrict__ enc,
                             const int* __restrict__ ids, float* sums) {
  int e = blockIdx.x * 256 + threadIdx.x;        // linear over enc [B,C,H,W]
  int c = (e >> 10) & 127;
  int b = e >> 17;
  int n = (b << 10) | (e & 1023);
  unsafeAtomicAdd(&sums[(size_t)ids[n] * C_DIM + c], enc[e]);
}

// ---------------- finalize: EMA weight + straight-through q ----------------
__global__ void finalize_w(const float* __restrict__ w,
                           const float* __restrict__ sums,
                           const float* __restrict__ counts,
                           float* __restrict__ outw) {
  int i = blockIdx.x * 256 + threadIdx.x;        // < K*C
  int k = i >> 7;
  const float omd = (float)(1.0 - 0.99);         // match python 1.0-0.99
  float mean = sums[i] / (counts[k] + 1e-12f);
  outw[i] = 0.99f * w[i] + omd * mean;
}
__global__ void write_q(const float* __restrict__ enc,
                        const float* __restrict__ w,
                        const int* __restrict__ ids, float* __restrict__ outq) {
  int e = blockIdx.x * 256 + threadIdx.x;
  int c = (e >> 10) & 127;
  int b = e >> 17;
  int n = (b << 10) | (e & 1023);
  float x = enc[e];
  float wq = w[(size_t)ids[n] * C_DIM + c];
  outq[e] = x + (wq - x);                        // same rounding as reference
}

// ---------------------------------------------------------------------------
extern "C" void kernel_launch(void* const* d_in, const int* in_sizes, int n_in,
                              void* d_out, int out_size, void* d_ws, size_t ws_size,
                              hipStream_t stream) {
  const float* enc = (const float*)d_in[0];      // [16,128,32,32]
  const float* w   = (const float*)d_in[1];      // [8192,128]
  float* out = (float*)d_out;
  float* out_ids = out;                          // 16384 (ids as float)
  float* out_q   = out + N_ROWS;                 // 2097152
  float* out_w   = out + N_ROWS + N_ROWS * C_DIM;// 1048576

  char* ws = (char*)d_ws;
  unsigned short* Ap   = (unsigned short*)(ws);                    // 12582912 B
  unsigned short* Bp   = (unsigned short*)(ws + 12582912);         //  6291456 B
  float*    xnorm      = (float*)(ws + 18874368);                  //    65536
  float*    wnorm      = (float*)(ws + 18939904);                  //    32768
  float*    pd1        = (float*)(ws + 18972672);                  //  4194304
  unsigned* pc1        = (unsigned*)(ws + 23166976);               //  4194304
  float*    pd2        = (float*)(ws + 27361280);                  //  4194304
  int*      ids        = (int*)(ws + 31555584);                    //    65536
  unsigned* flags      = (unsigned*)(ws + 31621120);               //    65536
  float*    counts     = (float*)(ws + 31686656);                  //    32768
  float*    sums       = (float*)(ws + 31719424);                  //  4194304
  (void)in_sizes; (void)n_in; (void)out_size; (void)ws_size;

  hipMemsetAsync(counts, 0, (K_CODES + K_CODES * C_DIM) * sizeof(float), stream);

  prep_x<<<N_ROWS / 4, 256, 0, stream>>>(enc, Ap, xnorm);
  prep_w<<<K_CODES / 4, 256, 0, stream>>>(w, Bp, wnorm);
  gemm_argmin<<<dim3(K_CODES / 128, N_ROWS / 128), 512, 0, stream>>>(
      Ap, Bp, xnorm, wnorm, pd1, pc1, pd2);
  merge_partials<<<N_ROWS / 256, 256, 0, stream>>>(pd1, pc1, pd2, ids, flags, out_ids);
  refine_rows<<<256, 256, 0, stream>>>(enc, w, wnorm, flags, ids, out_ids);
  scatter_counts<<<N_ROWS / 256, 256, 0, stream>>>(ids, counts);
  scatter_sums<<<(N_ROWS * C_DIM) / 256, 256, 0, stream>>>(enc, ids, sums);
  finalize_w<<<(K_CODES * C_DIM) / 256, 256, 0, stream>>>(w, sums, counts, out_w);
  write_q<<<(N_ROWS * C_DIM) / 256, 256, 0, stream>>>(enc, w, ids, out_q);
}

// Round 2
// 624.649 us; speedup vs baseline: 1.4887x; 1.4887x over previous
//
#include <hip/hip_runtime.h>
#include <stdint.h>
#include <stddef.h>

// ---------------------------------------------------------------------------
// VQ-VAE quantizer, MI355X.
// dist(n,k) = ||x_n||^2 + ||w_k||^2 - 2 x_n.w_k ; argmin_k fused into GEMM.
// fp32 emulated via bf16 split: A=[x_hi,x_hi,x_lo], B=[w_hi,w_lo,w_hi],
// inner dim 384 -> hi*hi + hi*lo + lo*hi (worst-case dist err ~1.4e-4).
// Rows with computed top-2 gap < TAU=3e-4 go on a worklist and get an exact
// fp32 full rescan (same arithmetic order as the R1-passing refine).
// GEMM: m97 structure — global_load_lds width=16, XOR-swizzled LDS chunks.
// ---------------------------------------------------------------------------

#define N_ROWS   16384      // B*H*W = 16*32*32
#define K_CODES  8192
#define C_DIM    128
#define KD       384        // packed inner dim (3 x 128)
#define TAU      3e-4f

typedef short s16x8 __attribute__((ext_vector_type(8)));
typedef float f32x4 __attribute__((ext_vector_type(4)));

static __device__ __forceinline__ unsigned short f2bf(float f) {
  unsigned u = __float_as_uint(f);
  u += 0x7fffu + ((u >> 16) & 1u);   // RNE
  return (unsigned short)(u >> 16);
}
static __device__ __forceinline__ float bf2f(unsigned short h) {
  return __uint_as_float(((unsigned)h) << 16);
}

// global -> LDS direct DMA, 16 B per lane; LDS dest = wave-uniform base + lane*16
#define GLDS16(g, l)                                              \
  __builtin_amdgcn_global_load_lds(                               \
      (const __attribute__((address_space(1))) unsigned int*)(g), \
      (__attribute__((address_space(3))) unsigned int*)(l), 16, 0, 0)

// ---------------- prep: pack encodings -> A [N, 384] bf16, xnorm -----------
// Coalesced: LDS-transpose 64 hw x 128 c per block.
__global__ __launch_bounds__(256) void prep_x(const float* __restrict__ enc,
                                              unsigned short* __restrict__ A,
                                              float* __restrict__ xnorm) {
  __shared__ float t[128][65];
  const int tid = threadIdx.x;
  const int b = blockIdx.x >> 4;
  const int hw0 = (blockIdx.x & 15) << 6;
  #pragma unroll
  for (int i = 0; i < 32; ++i) {
    int idx = i * 256 + tid;
    int c = idx >> 6, hwl = idx & 63;
    t[c][hwl] = enc[((size_t)(b * 128 + c) << 10) + hw0 + hwl];
  }
  __syncthreads();
  const int r = tid >> 2, sub = tid & 3;
  const int n = (b << 10) + hw0 + r;
  unsigned short* row = A + (size_t)n * KD;
  float s = 0.f;
  #pragma unroll
  for (int g = 0; g < 4; ++g) {
    s16x8 hv, lv;
    #pragma unroll
    for (int e = 0; e < 8; ++e) {
      float v = t[sub * 32 + g * 8 + e][r];
      s += v * v;
      unsigned short h = f2bf(v);
      hv[e] = (short)h;
      lv[e] = (short)f2bf(v - bf2f(h));
    }
    *(s16x8*)(row + sub * 32 + g * 8) = hv;        // [0:128)   hi
    *(s16x8*)(row + 128 + sub * 32 + g * 8) = hv;  // [128:256) hi
    *(s16x8*)(row + 256 + sub * 32 + g * 8) = lv;  // [256:384) lo
  }
  s += __shfl_xor(s, 1);
  s += __shfl_xor(s, 2);
  if (sub == 0) xnorm[n] = s;
}

// ---------------- prep: pack weight -> Bp [K, 384] bf16, wnorm -------------
__global__ void prep_w(const float* __restrict__ w,
                       unsigned short* __restrict__ Bp,
                       float* __restrict__ wnorm) {
  int wave = threadIdx.x >> 6, lane = threadIdx.x & 63;
  int k = blockIdx.x * 4 + wave;
  const float* base = w + (size_t)k * C_DIM;
  float x0 = base[lane], x1 = base[lane + 64];
  float s = x0 * x0 + x1 * x1;
  #pragma unroll
  for (int m = 1; m <= 32; m <<= 1) s += __shfl_xor(s, m);
  if (lane == 0) wnorm[k] = s;
  unsigned short h0 = f2bf(x0), h1 = f2bf(x1);
  unsigned short l0 = f2bf(x0 - bf2f(h0)), l1 = f2bf(x1 - bf2f(h1));
  unsigned short* row = Bp + (size_t)k * KD;
  row[lane]       = h0; row[lane + 64]  = h1;   // hi
  row[128 + lane] = l0; row[192 + lane] = l1;   // lo
  row[256 + lane] = h0; row[320 + lane] = h1;   // hi
}

// ---------------- main GEMM + fused per-row top-2 argmin -------------------
// 128x128 tile, 256 thr = 4 waves (2x2), wave tile 64x64 = 4x4 MFMA 16x16x32.
// BK=64: LDS [128][64] bf16 contiguous (global_load_lds forces lane order);
// chunk c16 of row r stored at slot (c16 ^ (r&7)) -> ds_read_b128 hits all
// 32 banks (8 lanes per 4-bank group = wave64 floor).
__global__ __launch_bounds__(256, 3) void gemm_argmin(
    const unsigned short* __restrict__ Ag, const unsigned short* __restrict__ Bg,
    const float* __restrict__ xnorm, const float* __restrict__ wnorm,
    float* __restrict__ pd1, unsigned* __restrict__ pc1, float* __restrict__ pd2)
{
  __shared__ __align__(16) unsigned short As[128 * 64];
  __shared__ __align__(16) unsigned short Bs[128 * 64];
  const int tid = threadIdx.x;
  const int lane = tid & 63, wave = tid >> 6;
  const int wr = wave >> 1, wc = wave & 1;       // wave grid 2 x 2
  const int m = lane & 15, q = lane >> 4;
  const int row0 = blockIdx.y * 128, col0 = blockIdx.x * 128;
  const int s_r = tid >> 3, s_j = tid & 7;       // staging row/chunk within issue

  f32x4 acc[4][4];
  #pragma unroll
  for (int i = 0; i < 4; ++i)
    #pragma unroll
    for (int j = 0; j < 4; ++j) acc[i][j] = (f32x4){0.f, 0.f, 0.f, 0.f};

  for (int kc = 0; kc < 6; ++kc) {
    if (kc) __syncthreads();                     // LDS reads of prev iter done
    #pragma unroll
    for (int i = 0; i < 4; ++i) {                // 4 issues x 256 thr x 16 B
      int r = i * 32 + s_r;
      int jc = s_j ^ (r & 7);                    // swizzled source chunk
      GLDS16(Ag + (size_t)(row0 + r) * KD + kc * 64 + jc * 8,
             As + (size_t)(i * 256 + wave * 64) * 8);
      GLDS16(Bg + (size_t)(col0 + r) * KD + kc * 64 + jc * 8,
             Bs + (size_t)(i * 256 + wave * 64) * 8);
    }
    __syncthreads();                             // drains vmcnt (DMA complete)
    #pragma unroll
    for (int ks = 0; ks < 2; ++ks) {
      s16x8 a[4], b[4];
      #pragma unroll
      for (int ti = 0; ti < 4; ++ti) {
        int r = wr * 64 + ti * 16 + m;
        int ch = (ks * 4 + q) ^ (r & 7);
        a[ti] = *(const s16x8*)(As + r * 64 + ch * 8);
      }
      #pragma unroll
      for (int tj = 0; tj < 4; ++tj) {
        int r = wc * 64 + tj * 16 + m;
        int ch = (ks * 4 + q) ^ (r & 7);
        b[tj] = *(const s16x8*)(Bs + r * 64 + ch * 8);
      }
      #pragma unroll
      for (int ti = 0; ti < 4; ++ti)
        #pragma unroll
        for (int tj = 0; tj < 4; ++tj)
          acc[ti][tj] = __builtin_amdgcn_mfma_f32_16x16x32_bf16(
              a[ti], b[tj], acc[ti][tj], 0, 0, 0);
    }
  }
  __syncthreads();

  // ---- epilogue: dist + per-row top2; C/D layout col=lane&15, row=4q+r ----
  float*    ed1 = (float*)As;                    // [2][128]
  unsigned* ec1 = (unsigned*)As + 256;
  float*    ed2 = (float*)As + 512;
  float wn[4];
  #pragma unroll
  for (int tj = 0; tj < 4; ++tj) wn[tj] = wnorm[col0 + wc * 64 + tj * 16 + m];

  #pragma unroll
  for (int ti = 0; ti < 4; ++ti) {
    #pragma unroll
    for (int r_ = 0; r_ < 4; ++r_) {
      int row_l = wr * 64 + ti * 16 + 4 * q + r_;
      float xn = xnorm[row0 + row_l];
      float d1 = __builtin_inff(), d2 = __builtin_inff();
      unsigned c1 = 0;
      #pragma unroll
      for (int tj = 0; tj < 4; ++tj) {           // ascending col; tie -> lower
        float dd = (xn + wn[tj]) - 2.0f * acc[ti][tj][r_];
        if (dd < d1) { d2 = d1; d1 = dd; c1 = (unsigned)(col0 + wc * 64 + tj * 16 + m); }
        else d2 = fminf(d2, dd);
      }
      #pragma unroll
      for (int s = 1; s <= 8; s <<= 1) {         // 16-lane butterfly over m
        float    od1 = __shfl_xor(d1, s);
        unsigned oc1 = (unsigned)__shfl_xor((int)c1, s);
        float    od2 = __shfl_xor(d2, s);
        float nd2 = fminf(fminf(d2, od2), fmaxf(d1, od1));
        if (od1 < d1 || (od1 == d1 && oc1 < c1)) { d1 = od1; c1 = oc1; }
        d2 = nd2;
      }
      if (m == 0) {
        ed1[wc * 128 + row_l] = d1;
        ec1[wc * 128 + row_l] = c1;
        ed2[wc * 128 + row_l] = d2;
      }
    }
  }
  __syncthreads();
  if (tid < 128) {                               // merge 2 col-halves (asc col)
    float d1 = ed1[tid]; unsigned c1 = ec1[tid]; float d2 = ed2[tid];
    float od1 = ed1[128 + tid], od2 = ed2[128 + tid];
    float nd2 = fminf(fminf(d2, od2), fmaxf(d1, od1));
    if (od1 < d1) { d1 = od1; c1 = ec1[128 + tid]; }
    d2 = nd2;
    size_t pi = (size_t)blockIdx.x * N_ROWS + (size_t)(row0 + tid);
    pd1[pi] = d1; pc1[pi] = c1; pd2[pi] = d2;
  }
}

// ---------------- merge partials across 64 colblocks + build worklist ------
__global__ void merge_partials(const float* __restrict__ pd1,
                               const unsigned* __restrict__ pc1,
                               const float* __restrict__ pd2,
                               int* __restrict__ ids, int* __restrict__ wlist,
                               unsigned* __restrict__ wcount,
                               float* __restrict__ out_ids) {
  int row = blockIdx.x * 256 + threadIdx.x;
  float d1 = pd1[row]; unsigned c1 = pc1[row]; float d2 = pd2[row];
  for (int cb = 1; cb < 64; ++cb) {              // ascending col -> first-min tie
    size_t i = (size_t)cb * N_ROWS + row;
    float od1 = pd1[i], od2 = pd2[i];
    float nd2 = fminf(fminf(d2, od2), fmaxf(d1, od1));
    if (od1 < d1) { d1 = od1; c1 = pc1[i]; }
    d2 = nd2;
  }
  ids[row] = (int)c1;
  out_ids[row] = (float)c1;
  if (d2 - d1 < TAU) {
    unsigned i = atomicAdd(wcount, 1u);
    wlist[i] = row;
  }
}

// ---------------- exact fp32 recompute for near-tie rows (worklist) --------
// One block per worklist row; arithmetic order identical to R1 (passing).
__global__ void refine_rows(const float* __restrict__ enc,
                            const float* __restrict__ w,
                            const float* __restrict__ wnorm,
                            const int* __restrict__ wlist,
                            const unsigned* __restrict__ wcount,
                            int* __restrict__ ids, float* __restrict__ out_ids) {
  __shared__ float xrow[C_DIM];
  __shared__ unsigned long long red[256];
  const int tid = threadIdx.x;
  const unsigned cnt = *wcount;
  for (unsigned wi = blockIdx.x; wi < cnt; wi += gridDim.x) {
    int row = wlist[wi];
    int b = row >> 10, hw = row & 1023;
    if (tid < C_DIM) xrow[tid] = enc[((size_t)(b * 128 + tid)) * 1024 + hw];
    __syncthreads();
    float xn = 0.f;
    for (int c = 0; c < C_DIM; ++c) xn += xrow[c] * xrow[c];
    unsigned long long best = ~0ull;
    for (int k = tid; k < K_CODES; k += 256) {
      const float4* wk = (const float4*)(w + (size_t)k * C_DIM);
      float S = 0.f;
      #pragma unroll
      for (int c4 = 0; c4 < 32; ++c4) {          // same order as scalar R1 loop
        float4 v = wk[c4];
        S = fmaf(xrow[c4 * 4 + 0], v.x, S);
        S = fmaf(xrow[c4 * 4 + 1], v.y, S);
        S = fmaf(xrow[c4 * 4 + 2], v.z, S);
        S = fmaf(xrow[c4 * 4 + 3], v.w, S);
      }
      float d = (xn + wnorm[k]) - 2.0f * S;
      unsigned long long key =
          ((unsigned long long)__float_as_uint(d) << 32) | (unsigned)k;
      best = best < key ? best : key;            // d>0 -> bits monotone; tie->low k
    }
    red[tid] = best;
    __syncthreads();
    for (int s = 128; s > 0; s >>= 1) {
      if (tid < s) red[tid] = red[tid] < red[tid + s] ? red[tid] : red[tid + s];
      __syncthreads();
    }
    if (tid == 0) {
      int k = (int)(red[0] & 0xffffffffu);
      ids[row] = k;
      out_ids[row] = (float)k;
    }
    __syncthreads();
  }
}

// ---------------- scatter stats --------------------------------------------
__global__ void scatter_counts(const int* __restrict__ ids, float* counts) {
  int n = blockIdx.x * 256 + threadIdx.x;
  unsafeAtomicAdd(&counts[ids[n]], 1.0f);
}
__global__ void scatter_sums(const float* __restrict__ enc,
                             const int* __restrict__ ids, float* sums) {
  int e = blockIdx.x * 256 + threadIdx.x;        // linear over enc [B,C,H,W]
  int c = (e >> 10) & 127;
  int b = e >> 17;
  int n = (b << 10) | (e & 1023);
  unsafeAtomicAdd(&sums[(size_t)ids[n] * C_DIM + c], enc[e]);
}

// ---------------- finalize: EMA weight + straight-through q ----------------
__global__ void finalize_w(const float* __restrict__ w,
                           const float* __restrict__ sums,
                           const float* __restrict__ counts,
                           float* __restrict__ outw) {
  int i = blockIdx.x * 256 + threadIdx.x;        // < K*C
  int k = i >> 7;
  const float omd = (float)(1.0 - 0.99);
  float mean = sums[i] / (counts[k] + 1e-12f);
  outw[i] = 0.99f * w[i] + omd * mean;
}
__global__ void write_q(const float* __restrict__ enc,
                        const float* __restrict__ w,
                        const int* __restrict__ ids, float* __restrict__ outq) {
  int e = blockIdx.x * 256 + threadIdx.x;
  int c = (e >> 10) & 127;
  int b = e >> 17;
  int n = (b << 10) | (e & 1023);
  float x = enc[e];
  float wq = w[(size_t)ids[n] * C_DIM + c];
  outq[e] = x + (wq - x);
}

// ---------------------------------------------------------------------------
extern "C" void kernel_launch(void* const* d_in, const int* in_sizes, int n_in,
                              void* d_out, int out_size, void* d_ws, size_t ws_size,
                              hipStream_t stream) {
  const float* enc = (const float*)d_in[0];      // [16,128,32,32]
  const float* w   = (const float*)d_in[1];      // [8192,128]
  float* out = (float*)d_out;
  float* out_ids = out;                          // 16384 (ids as float)
  float* out_q   = out + N_ROWS;                 // 2097152
  float* out_w   = out + N_ROWS + N_ROWS * C_DIM;// 1048576

  char* ws = (char*)d_ws;
  unsigned short* Ap = (unsigned short*)(ws);                      // 12582912 B
  unsigned short* Bp = (unsigned short*)(ws + 12582912);           //  6291456 B
  float*    xnorm    = (float*)(ws + 18874368);                    //    65536
  float*    wnorm    = (float*)(ws + 18939904);                    //    32768
  float*    pd1      = (float*)(ws + 18972672);                    //  4194304
  unsigned* pc1      = (unsigned*)(ws + 23166976);                 //  4194304
  float*    pd2      = (float*)(ws + 27361280);                    //  4194304
  int*      ids      = (int*)(ws + 31555584);                      //    65536
  int*      wlist    = (int*)(ws + 31621120);                      //    65536
  float*    counts   = (float*)(ws + 31686656);                    //    32768
  float*    sums     = (float*)(ws + 31719424);                    //  4194304
  unsigned* wcount   = (unsigned*)(ws + 35913728);                 //        4
  (void)in_sizes; (void)n_in; (void)out_size; (void)ws_size;

  // zero counts + sums + wcount (contiguous)
  hipMemsetAsync(counts, 0, 32768 + 4194304 + 4, stream);

  prep_x<<<256, 256, 0, stream>>>(enc, Ap, xnorm);
  prep_w<<<K_CODES / 4, 256, 0, stream>>>(w, Bp, wnorm);
  gemm_argmin<<<dim3(K_CODES / 128, N_ROWS / 128), 256, 0, stream>>>(
      Ap, Bp, xnorm, wnorm, pd1, pc1, pd2);
  merge_partials<<<N_ROWS / 256, 256, 0, stream>>>(pd1, pc1, pd2, ids, wlist,
                                                   wcount, out_ids);
  refine_rows<<<256, 256, 0, stream>>>(enc, w, wnorm, wlist, wcount, ids, out_ids);
  scatter_counts<<<N_ROWS / 256, 256, 0, stream>>>(ids, counts);
  scatter_sums<<<(N_ROWS * C_DIM) / 256, 256, 0, stream>>>(enc, ids, sums);
  finalize_w<<<(K_CODES * C_DIM) / 256, 256, 0, stream>>>(w, sums, counts, out_w);
  write_q<<<(N_ROWS * C_DIM) / 256, 256, 0, stream>>>(enc, w, ids, out_q);
}